// Round 13
// baseline (22057.265 us; speedup 1.0000x reference)
//
#include <hip/hip_runtime.h>
#include <stdint.h>

typedef unsigned int u32;
typedef float  f32x4 __attribute__((ext_vector_type(4)));
typedef float  f32x2 __attribute__((ext_vector_type(2)));
typedef double f64x2 __attribute__((ext_vector_type(2)));
typedef double f64x4 __attribute__((ext_vector_type(4)));

constexpr int NT = 256;   // threads per block
constexpr int BB = 256;   // batch
constexpr int ZD = 256;
constexpr int TD = 512;
constexpr int CF = 1024;
constexpr int G4 = 4096;
constexpr int NA = 64;
constexpr int NSTEP = 64;
constexpr int TS_OFF = BB * NSTEP * NA;   // acts [256][64][64] then ts [256][64]

// k_pre LDS cores (round-3 proven): RSF=34 f64 (16B-aligned rows), FRS=68 f32 + XOR swizzle.
constexpr int RSF = 34;
constexpr int FRS = 68;
constexpr int SMEMB = 2 * 64 * RSF * 8;   // 34816 B

// k_stepA: DIRECT-FROM-GLOBAL GEMMs — no LDS, no barriers (rounds 6-12 showed the
// barrier/staging skeleton, not any pipe, is the 170us floor; all pipes <35% busy).
// Operand values and MFMA/fmaf ordering are bit-identical to the LDS versions.

struct P {
  const float *z, *W_z2t, *b_z2t, *E, *Wih_a, *Whh_a, *bih_a, *bhh_a,
              *Wih_t, *Whh_t, *bih_t, *bhh_t, *W_act, *b_act, *W_ts1, *b_ts1, *W_ts2, *b_ts2;
  float* out;                                               // float32 output (ref dtype)
  // f64 argmax-critical path
  double *t_rec64, *pre_a64, *E_proj_a64, *h_a64, *c_a64, *gacc_a;  // h_a64 dbuf [2][256][1024]
  // f32 ts path
  float *t_rec32, *pre_t, *E_proj_t, *colt, *h_t, *c_t, *gacc_t, *ts_accum;  // h_t dbuf [2][..]
  int* idxb;
};

__device__ __forceinline__ float sigf(float x){ return 1.f / (1.f + expf(-x)); }
__device__ __forceinline__ float tanhf_(float x){
  float ax = fabsf(x); float e = expf(-2.f * ax);
  float t = 1.f - 2.f * e / (1.f + e);
  return x < 0.f ? -t : t;
}
__device__ __forceinline__ double sigd(double x){ return 1.0 / (1.0 + exp(-x)); }

// ---------------- setup: t_rec (f64+f32), state init ----------------
__global__ void __launch_bounds__(NT) k_setup(P p){
  __shared__ double sz[ZD];
  const int bid = blockIdx.x, tid = threadIdx.x;
  for (int i = tid; i < ZD; i += NT) sz[i] = (double)p.z[bid * ZD + i];
  __syncthreads();
  for (int k = tid; k < TD; k += NT){
    const float* wr = p.W_z2t + (size_t)k * ZD;
    double a = 0.0;
    for (int j = 0; j < ZD; ++j) a = fma((double)wr[j], sz[j], a);
    a += (double)p.b_z2t[k];
    double t = a > 0.0 ? a : 0.0;
    p.t_rec64[(size_t)bid * TD + k] = t;
    p.t_rec32[(size_t)bid * TD + k] = (float)t;
  }
  for (int i = tid; i < CF; i += NT){
    p.c_a64[(size_t)bid * CF + i] = 0.0;
    p.h_a64[(size_t)bid * CF + i] = 0.0;  // buffer 0
    p.c_t[(size_t)bid * CF + i] = 0.f;
    p.h_t[(size_t)bid * CF + i] = 0.f;    // buffer 0
  }
  if (tid == 0){ p.idxb[bid] = NA - 1; p.ts_accum[bid] = 0.f; }
}

// ---------------- E_proj tables + colt. grid 528 ----------------
__global__ void __launch_bounds__(NT) k_eproj(P p){
  __shared__ double sz[ZD];
  const int bid = blockIdx.x, tid = threadIdx.x;
  if (bid < 256){            // E_proj_a64: row bid>>2, col chunk bid&3 (1024 cols)
    const int erow = bid >> 2, cchunk = bid & 3;
    for (int i = tid; i < ZD; i += NT) sz[i] = (double)p.E[erow * ZD + i];
    __syncthreads();
    for (int ci = 0; ci < 4; ++ci){
      const int c = cchunk * 1024 + ci * 256 + tid;
      const float* wr = p.Wih_a + (size_t)c * 768 + 512;
      double a = 0.0;
      for (int j = 0; j < 256; ++j) a = fma((double)wr[j], sz[j], a);
      p.E_proj_a64[(size_t)erow * G4 + c] = a;
    }
  } else if (bid < 512){     // E_proj_t (f32)
    const int erow = (bid - 256) >> 2, cchunk = (bid - 256) & 3;
    for (int i = tid; i < ZD; i += NT) sz[i] = (double)p.E[erow * ZD + i];
    __syncthreads();
    for (int ci = 0; ci < 4; ++ci){
      const int c = cchunk * 1024 + ci * 256 + tid;
      const float* wr = p.Wih_t + (size_t)c * 769 + 512;
      float a = 0.f;
      for (int j = 0; j < 256; ++j) a = fmaf(wr[j], (float)sz[j], a);
      p.E_proj_t[(size_t)erow * G4 + c] = a;
    }
  } else {                   // colt
    const int c = (bid - 512) * 256 + tid;
    p.colt[c] = p.Wih_t[(size_t)c * 769 + 768];
  }
}

// ---------------- k_pre f64 MFMA core (LDS, round-3 proven; odd ldb ok) ----------------
template <bool A64, bool OUT64>
__device__ void mgemm64(char* smem, const void* __restrict__ Av, int lda,
                        const float* __restrict__ B, int ldb,
                        int rowb, int colb, int K,
                        const float* __restrict__ bih, const float* __restrict__ bhh,
                        void* __restrict__ outv){
  double* As = (double*)smem;
  double* Bs = As + 64 * RSF;
  const int tid = threadIdx.x;
  const int lane = tid & 63;
  const int wm = (tid >> 7) & 1, wn = (tid >> 6) & 1;
  const int m = lane & 15, q = lane >> 4;
  const int tr = tid >> 2, tkq = tid & 3;
  const double* A64p = (const double*)Av;
  const float*  A32p = (const float*)Av;

  double av[8], bv[8];
  auto loadchunk = [&](int kb){
    if (A64){
      const double* ap = A64p + (size_t)(rowb + tr) * lda + kb + tkq * 8;
      #pragma unroll
      for (int j = 0; j < 8; ++j) av[j] = ap[j];
    } else {
      const float* ap = A32p + (size_t)(rowb + tr) * lda + kb + tkq * 8;
      #pragma unroll
      for (int j = 0; j < 8; ++j) av[j] = (double)ap[j];
    }
    const float* bp = B + (size_t)(colb + tr) * ldb + kb + tkq * 8;
    #pragma unroll
    for (int j = 0; j < 8; ++j) bv[j] = (double)bp[j];
  };
  f64x4 acc[2][2];
  #pragma unroll
  for (int g = 0; g < 2; ++g)
    #pragma unroll
    for (int h = 0; h < 2; ++h) acc[g][h] = f64x4{0.0,0.0,0.0,0.0};

  loadchunk(0);
  for (int kb = 0; kb < K; kb += 32){
    __syncthreads();
    {
      double* arow = As + tr * RSF + tkq * 8;
      double* brow = Bs + tr * RSF + tkq * 8;
      #pragma unroll
      for (int j = 0; j < 4; ++j){
        *(f64x2*)(arow + j * 2) = f64x2{av[j], av[j + 4]};
        *(f64x2*)(brow + j * 2) = f64x2{bv[j], bv[j + 4]};
      }
    }
    __syncthreads();
    if (kb + 32 < K) loadchunk(kb + 32);
    #pragma unroll
    for (int sp = 0; sp < 4; ++sp){
      const f64x2 a0 = *(const f64x2*)(As + (wm * 32 +  0 + m) * RSF + sp * 8 + q * 2);
      const f64x2 a1 = *(const f64x2*)(As + (wm * 32 + 16 + m) * RSF + sp * 8 + q * 2);
      const f64x2 b0 = *(const f64x2*)(Bs + (wn * 32 +  0 + m) * RSF + sp * 8 + q * 2);
      const f64x2 b1 = *(const f64x2*)(Bs + (wn * 32 + 16 + m) * RSF + sp * 8 + q * 2);
      acc[0][0] = __builtin_amdgcn_mfma_f64_16x16x4f64(a0[0], b0[0], acc[0][0], 0, 0, 0);
      acc[0][1] = __builtin_amdgcn_mfma_f64_16x16x4f64(a0[0], b1[0], acc[0][1], 0, 0, 0);
      acc[1][0] = __builtin_amdgcn_mfma_f64_16x16x4f64(a1[0], b0[0], acc[1][0], 0, 0, 0);
      acc[1][1] = __builtin_amdgcn_mfma_f64_16x16x4f64(a1[0], b1[0], acc[1][1], 0, 0, 0);
      acc[0][0] = __builtin_amdgcn_mfma_f64_16x16x4f64(a0[1], b0[1], acc[0][0], 0, 0, 0);
      acc[0][1] = __builtin_amdgcn_mfma_f64_16x16x4f64(a0[1], b1[1], acc[0][1], 0, 0, 0);
      acc[1][0] = __builtin_amdgcn_mfma_f64_16x16x4f64(a1[1], b0[1], acc[1][0], 0, 0, 0);
      acc[1][1] = __builtin_amdgcn_mfma_f64_16x16x4f64(a1[1], b1[1], acc[1][1], 0, 0, 0);
    }
  }
  #pragma unroll
  for (int g = 0; g < 2; ++g){
    const int rb = rowb + wm * 32 + g * 16 + q;
    #pragma unroll
    for (int h = 0; h < 2; ++h){
      const int cc = colb + wn * 32 + h * 16 + m;
      const double bb = (double)bih[cc] + (double)bhh[cc];
      #pragma unroll
      for (int v = 0; v < 4; ++v){
        if (OUT64) ((double*)outv)[(size_t)(rb + 4 * v) * G4 + cc] = acc[g][h][v] + bb;
        else       ((float*) outv)[(size_t)(rb + 4 * v) * G4 + cc] = (float)(acc[g][h][v] + bb);
      }
    }
  }
}

// ---------------- k_pre f32 core (LDS + XOR swizzle, round-12 proven; odd ldb ok) ----------------
__device__ void dgemm32(char* smem, const float* __restrict__ A, int lda,
                        const float* __restrict__ B, int ldb,
                        int rowb, int colb, int K,
                        const float* __restrict__ bih, const float* __restrict__ bhh,
                        float* __restrict__ outp){
  float* As = (float*)smem;                       // [64][FRS]
  float* Bs = (float*)(smem + 64 * FRS * 4);      // [64][FRS]
  const int tid = threadIdx.x;
  const int tx = tid & 15, ty = tid >> 4;
  const int r_ = tid >> 2, kq = tid & 3;
  const int wsw = r_ ^ (kq * 8);
  float acc[4][4];
  #pragma unroll
  for (int i = 0; i < 4; ++i)
    #pragma unroll
    for (int j = 0; j < 4; ++j) acc[i][j] = 0.f;

  float pa[16], pb[16];
  auto ldA = [&](int kb){
    const float* ap = A + (size_t)(rowb + r_) * lda + kb + kq * 16;
    #pragma unroll
    for (int j = 0; j < 16; ++j) pa[j] = ap[j];
  };
  auto ldB = [&](int kb){
    const float* bp = B + (size_t)(colb + r_) * ldb + kb + kq * 16;
    #pragma unroll
    for (int j = 0; j < 16; ++j) pb[j] = bp[j];
  };
  ldA(0); ldB(0);
  for (int kb = 0; kb < K; kb += 64){
    __syncthreads();
    #pragma unroll
    for (int j = 0; j < 16; ++j){
      As[(kq * 16 + j) * FRS + wsw] = pa[j];
      Bs[(kq * 16 + j) * FRS + wsw] = pb[j];
    }
    __syncthreads();
    if (kb + 64 < K){ ldA(kb + 64); ldB(kb + 64); }
    #pragma unroll 4
    for (int k = 0; k < 64; ++k){
      const int sw = (k >> 4) * 8;
      f32x4 a4 = *(const f32x4*)(As + k * FRS + ((4 * ty) ^ sw));
      f32x4 b4 = *(const f32x4*)(Bs + k * FRS + ((4 * tx) ^ sw));
      acc[0][0] = fmaf(a4[0], b4[0], acc[0][0]); acc[0][1] = fmaf(a4[0], b4[1], acc[0][1]);
      acc[0][2] = fmaf(a4[0], b4[2], acc[0][2]); acc[0][3] = fmaf(a4[0], b4[3], acc[0][3]);
      acc[1][0] = fmaf(a4[1], b4[0], acc[1][0]); acc[1][1] = fmaf(a4[1], b4[1], acc[1][1]);
      acc[1][2] = fmaf(a4[1], b4[2], acc[1][2]); acc[1][3] = fmaf(a4[1], b4[3], acc[1][3]);
      acc[2][0] = fmaf(a4[2], b4[0], acc[2][0]); acc[2][1] = fmaf(a4[2], b4[1], acc[2][1]);
      acc[2][2] = fmaf(a4[2], b4[2], acc[2][2]); acc[2][3] = fmaf(a4[2], b4[3], acc[2][3]);
      acc[3][0] = fmaf(a4[3], b4[0], acc[3][0]); acc[3][1] = fmaf(a4[3], b4[1], acc[3][1]);
      acc[3][2] = fmaf(a4[3], b4[2], acc[3][2]); acc[3][3] = fmaf(a4[3], b4[3], acc[3][3]);
    }
  }
  const int c0 = colb + 4 * tx;
  float bb0 = bih[c0+0] + bhh[c0+0], bb1 = bih[c0+1] + bhh[c0+1];
  float bb2 = bih[c0+2] + bhh[c0+2], bb3 = bih[c0+3] + bhh[c0+3];
  #pragma unroll
  for (int i = 0; i < 4; ++i){
    float* o = outp + (size_t)(rowb + 4 * ty + i) * G4 + c0;
    o[0] = acc[i][0] + bb0; o[1] = acc[i][1] + bb1;
    o[2] = acc[i][2] + bb2; o[3] = acc[i][3] + bb3;
  }
}

// ---------------- stepA a-core: DIRECT f64 MFMA GEMM (no LDS, no barriers) ----------------
// Same fragment mapping and MFMA order as mgemm64 (bit-identical); operands loaded
// straight from global (L1/L2-hot). 1-group-deep X/Y register prefetch. K mult of 16.
template <bool A64, bool OUT64>
__device__ void mgemm64d(const void* __restrict__ Av, int lda,
                         const float* __restrict__ B, int ldb,
                         int rowb, int colb, int K,
                         const void* __restrict__ addin, void* __restrict__ outv){
  const int tid = threadIdx.x, lane = tid & 63;
  const int wm = (tid >> 7) & 1, wn = (tid >> 6) & 1;
  const int m = lane & 15, q = lane >> 4;
  const double* Ar0 = (const double*)Av + (size_t)(rowb + wm * 32 +  0 + m) * lda;
  const double* Ar1 = (const double*)Av + (size_t)(rowb + wm * 32 + 16 + m) * lda;
  const float*  Af0 = (const float*) Av + (size_t)(rowb + wm * 32 +  0 + m) * lda;
  const float*  Af1 = (const float*) Av + (size_t)(rowb + wm * 32 + 16 + m) * lda;
  const float*  Bc0 = B + (size_t)(colb + wn * 32 +  0 + m) * ldb;
  const float*  Bc1 = B + (size_t)(colb + wn * 32 + 16 + m) * ldb;
  f64x4 c00{0,0,0,0}, c01{0,0,0,0}, c10{0,0,0,0}, c11{0,0,0,0};
  double xA00,xA04,xA10,xA14,xB00,xB04,xB10,xB14;
  double yA00,yA04,yA10,yA14,yB00,yB04,yB10,yB14;
#define ALD(S, g) do{ const int _k = 8 * (g) + q;                                 \
    S##A00 = A64 ? Ar0[_k]     : (double)Af0[_k];                                 \
    S##A04 = A64 ? Ar0[_k + 4] : (double)Af0[_k + 4];                             \
    S##A10 = A64 ? Ar1[_k]     : (double)Af1[_k];                                 \
    S##A14 = A64 ? Ar1[_k + 4] : (double)Af1[_k + 4];                             \
    S##B00 = (double)Bc0[_k];   S##B04 = (double)Bc0[_k + 4];                     \
    S##B10 = (double)Bc1[_k];   S##B14 = (double)Bc1[_k + 4]; }while(0)
#define AMF(S) do{                                                                \
    c00 = __builtin_amdgcn_mfma_f64_16x16x4f64(S##A00, S##B00, c00, 0, 0, 0);     \
    c01 = __builtin_amdgcn_mfma_f64_16x16x4f64(S##A00, S##B10, c01, 0, 0, 0);     \
    c10 = __builtin_amdgcn_mfma_f64_16x16x4f64(S##A10, S##B00, c10, 0, 0, 0);     \
    c11 = __builtin_amdgcn_mfma_f64_16x16x4f64(S##A10, S##B10, c11, 0, 0, 0);     \
    c00 = __builtin_amdgcn_mfma_f64_16x16x4f64(S##A04, S##B04, c00, 0, 0, 0);     \
    c01 = __builtin_amdgcn_mfma_f64_16x16x4f64(S##A04, S##B14, c01, 0, 0, 0);     \
    c10 = __builtin_amdgcn_mfma_f64_16x16x4f64(S##A14, S##B04, c10, 0, 0, 0);     \
    c11 = __builtin_amdgcn_mfma_f64_16x16x4f64(S##A14, S##B14, c11, 0, 0, 0); }while(0)
  const int NG = K >> 3;                         // even (K = 512 or 1024)
  ALD(x, 0);
  for (int g = 0; g < NG; g += 2){
    ALD(y, g + 1);
    AMF(x);
    if (g + 2 < NG) ALD(x, g + 2);
    AMF(y);
  }
#undef ALD
#undef AMF
  // epilogue, HW-verified H2 layout: reg v -> row base + q + 4v, col base + m
  #pragma unroll
  for (int g = 0; g < 2; ++g){
    const int rb = rowb + wm * 32 + g * 16 + q;
    #pragma unroll
    for (int h = 0; h < 2; ++h){
      const f64x4 a = g ? (h ? c11 : c10) : (h ? c01 : c00);
      const int cc = colb + wn * 32 + h * 16 + m;
      #pragma unroll
      for (int v = 0; v < 4; ++v){
        const size_t o = (size_t)(rb + 4 * v) * G4 + cc;
        if (OUT64) ((double*)outv)[o] = a[v] + ((const double*)addin)[o];
        else       ((float*) outv)[o] = (float)(a[v] + (double)((const float*)addin)[o]);
      }
    }
  }
}

// ---------------- stepA t-core: DIRECT f32 GEMM (no LDS, no barriers) ----------------
// Same per-output ascending-k fmaf chain as dgemm32 (bit-identical). 4 A-rows + 4 B-cols
// per thread, f32x4 quads, 1-quad-deep X/Y register prefetch. lda/ldb mult of 4.
__device__ void dgemm32d(const float* __restrict__ A, int lda,
                         const float* __restrict__ B, int ldb,
                         int rowb, int colb, int K,
                         const float* __restrict__ addin, float* __restrict__ outp){
  const int tid = threadIdx.x;
  const int tx = tid & 15, ty = tid >> 4;
  const float* ar0 = A + (size_t)(rowb + 4 * ty + 0) * lda;
  const float* ar1 = A + (size_t)(rowb + 4 * ty + 1) * lda;
  const float* ar2 = A + (size_t)(rowb + 4 * ty + 2) * lda;
  const float* ar3 = A + (size_t)(rowb + 4 * ty + 3) * lda;
  const float* br0 = B + (size_t)(colb + 4 * tx + 0) * ldb;
  const float* br1 = B + (size_t)(colb + 4 * tx + 1) * ldb;
  const float* br2 = B + (size_t)(colb + 4 * tx + 2) * ldb;
  const float* br3 = B + (size_t)(colb + 4 * tx + 3) * ldb;
  float acc[4][4];
  #pragma unroll
  for (int i = 0; i < 4; ++i)
    #pragma unroll
    for (int j = 0; j < 4; ++j) acc[i][j] = 0.f;
  f32x4 xa0,xa1,xa2,xa3, xb0,xb1,xb2,xb3;
  f32x4 ya0,ya1,ya2,ya3, yb0,yb1,yb2,yb3;
#define TLD(S, kk) do{                                                            \
    S##a0 = *(const f32x4*)(ar0 + (kk)); S##a1 = *(const f32x4*)(ar1 + (kk));     \
    S##a2 = *(const f32x4*)(ar2 + (kk)); S##a3 = *(const f32x4*)(ar3 + (kk));     \
    S##b0 = *(const f32x4*)(br0 + (kk)); S##b1 = *(const f32x4*)(br1 + (kk));     \
    S##b2 = *(const f32x4*)(br2 + (kk)); S##b3 = *(const f32x4*)(br3 + (kk)); }while(0)
#define TFMA(S) do{ _Pragma("unroll")                                             \
    for (int _kk = 0; _kk < 4; ++_kk){                                            \
      acc[0][0]=fmaf(S##a0[_kk],S##b0[_kk],acc[0][0]); acc[0][1]=fmaf(S##a0[_kk],S##b1[_kk],acc[0][1]); \
      acc[0][2]=fmaf(S##a0[_kk],S##b2[_kk],acc[0][2]); acc[0][3]=fmaf(S##a0[_kk],S##b3[_kk],acc[0][3]); \
      acc[1][0]=fmaf(S##a1[_kk],S##b0[_kk],acc[1][0]); acc[1][1]=fmaf(S##a1[_kk],S##b1[_kk],acc[1][1]); \
      acc[1][2]=fmaf(S##a1[_kk],S##b2[_kk],acc[1][2]); acc[1][3]=fmaf(S##a1[_kk],S##b3[_kk],acc[1][3]); \
      acc[2][0]=fmaf(S##a2[_kk],S##b0[_kk],acc[2][0]); acc[2][1]=fmaf(S##a2[_kk],S##b1[_kk],acc[2][1]); \
      acc[2][2]=fmaf(S##a2[_kk],S##b2[_kk],acc[2][2]); acc[2][3]=fmaf(S##a2[_kk],S##b3[_kk],acc[2][3]); \
      acc[3][0]=fmaf(S##a3[_kk],S##b0[_kk],acc[3][0]); acc[3][1]=fmaf(S##a3[_kk],S##b1[_kk],acc[3][1]); \
      acc[3][2]=fmaf(S##a3[_kk],S##b2[_kk],acc[3][2]); acc[3][3]=fmaf(S##a3[_kk],S##b3[_kk],acc[3][3]); } }while(0)
  TLD(x, 0);
  for (int kb = 0; kb < K; kb += 8){             // K mult of 8
    TLD(y, kb + 4);
    TFMA(x);
    if (kb + 8 < K) TLD(x, kb + 8);
    TFMA(y);
  }
#undef TLD
#undef TFMA
  const int c0 = colb + 4 * tx;
  #pragma unroll
  for (int i = 0; i < 4; ++i){
    const size_t base = (size_t)(rowb + 4 * ty + i) * G4 + c0;
    const float* ai = addin + base;
    float* o = outp + base;
    o[0] = acc[i][0] + ai[0]; o[1] = acc[i][1] + ai[1];
    o[2] = acc[i][2] + ai[2]; o[3] = acc[i][3] + ai[3];
  }
}

// ---------------- ts head, j-split (relu-safe): 512 jobs of 8 j-rows ----------------
__device__ void tshead_j(const P& p, int bid, int hbuf){
  const int tid = threadIdx.x;
  const int tm = bid >> 6, tjq = bid & 63;
  const int rowb = tm * 32;
  const int rt = tid >> 3, j8 = tid & 7;
  const int j = tjq * 8 + j8;
  const float* __restrict__ hr = p.h_t + (size_t)hbuf * BB * CF + (size_t)(rowb + rt) * CF;
  const float* __restrict__ wr = p.W_ts1 + (size_t)j * CF;
  float a0=0,a1=0,a2=0,a3=0;
  for (int k = 0; k < CF; k += 16){
    f32x4 h0 = *(const f32x4*)(hr + k),     h1 = *(const f32x4*)(hr + k + 4);
    f32x4 h2 = *(const f32x4*)(hr + k + 8), h3 = *(const f32x4*)(hr + k + 12);
    f32x4 w0 = *(const f32x4*)(wr + k),     w1 = *(const f32x4*)(wr + k + 4);
    f32x4 w2 = *(const f32x4*)(wr + k + 8), w3 = *(const f32x4*)(wr + k + 12);
    a0 = fmaf(h0[0],w0[0], fmaf(h0[1],w0[1], fmaf(h0[2],w0[2], fmaf(h0[3],w0[3], a0))));
    a1 = fmaf(h1[0],w1[0], fmaf(h1[1],w1[1], fmaf(h1[2],w1[2], fmaf(h1[3],w1[3], a1))));
    a2 = fmaf(h2[0],w2[0], fmaf(h2[1],w2[1], fmaf(h2[2],w2[2], fmaf(h2[3],w2[3], a2))));
    a3 = fmaf(h3[0],w3[0], fmaf(h3[1],w3[1], fmaf(h3[2],w3[2], fmaf(h3[3],w3[3], a3))));
  }
  float v = ((a0 + a1) + (a2 + a3)) + p.b_ts1[j];
  v = (v > 0.f ? v : 0.f) * p.W_ts2[j];
  v += __shfl_xor(v, 1, 64);
  v += __shfl_xor(v, 2, 64);
  v += __shfl_xor(v, 4, 64);
  if (j8 == 0) atomicAdd(p.ts_accum + rowb + rt, v);
}

// ---------------- pre kernel (LDS cores, odd ldb). grid 512 ----------------
__global__ void __launch_bounds__(NT) k_pre(P p){
  __shared__ __align__(16) char smem[SMEMB];
  const int bid = blockIdx.x;
  const int hsel = bid >> 8, sub = bid & 255;
  const int rowb = (sub >> 6) * 64, colb = (sub & 63) * 64;
  if (hsel == 0)
    mgemm64<true, true>(smem, p.t_rec64, TD, p.Wih_a, 768, rowb, colb, TD,
                        p.bih_a, p.bhh_a, p.pre_a64);
  else
    dgemm32(smem, p.t_rec32, TD, p.Wih_t, 769, rowb, colb, TD,
            p.bih_t, p.bhh_t, p.pre_t);
}

// ---------------- step A: ts head + DIRECT recurrent GEMMs (no LDS/barriers). grid 512 ----------------
__global__ void __launch_bounds__(NT) k_stepA(P p, int s){
  const int bid = blockIdx.x;
  if (s > 0) tshead_j(p, bid, s & 1);           // ts head for step s-1
  const int hsel = bid >> 8, sub = bid & 255;
  const int rowb = (sub >> 6) * 64, colb = (sub & 63) * 64;   // colb fast -> XCD-stable
  const int rd = s & 1;
  if (hsel == 0)
    mgemm64d<true, true>(p.h_a64 + (size_t)rd * BB * CF, CF, p.Whh_a, CF,
                         rowb, colb, CF, p.pre_a64, p.gacc_a);
  else
    dgemm32d(p.h_t + (size_t)rd * BB * CF, CF, p.Whh_t, CF,
             rowb, colb, CF, p.pre_t, p.gacc_t);
}

// ---------------- step B: LSTM-a pointwise (f64) + logits/argmax/softmax (f64) + LSTM-t (f32) ----------------
__global__ void __launch_bounds__(NT) k_stepB(P p, int s){
  __shared__ double shd[1092];
  const int b = blockIdx.x, tid = threadIdx.x;
  const int cur = (s + 1) & 1;   // h_a/h_t write buffer
  int idxp = p.idxb[b];
  idxp = idxp < 0 ? 0 : (idxp > 63 ? 63 : idxp);
  {
    const double* ga = p.gacc_a + (size_t)b * G4;       // includes pre_a (biases folded)
    const double* ea = p.E_proj_a64 + (size_t)idxp * G4;
    const int c0 = tid * 4;
    #pragma unroll
    for (int jj = 0; jj < 4; ++jj){
      const int c = c0 + jj;
      double gi = ga[0*CF + c] + ea[0*CF + c];
      double gf = ga[1*CF + c] + ea[1*CF + c];
      double gg = ga[2*CF + c] + ea[2*CF + c];
      double go = ga[3*CF + c] + ea[3*CF + c];
      double cv = p.c_a64[(size_t)b * CF + c];
      double cn = sigd(gf) * cv + sigd(gi) * tanh(gg);
      double hn = sigd(go) * tanh(cn);
      p.c_a64[(size_t)b * CF + c] = cn;
      p.h_a64[(size_t)cur * BB * CF + (size_t)b * CF + c] = hn;
      shd[c] = hn;
    }
  }
  if (tid == 0) shd[1088] = (s == 0) ? 0.0 : ((double)p.ts_accum[b] + (double)p.b_ts2[0]);
  __syncthreads();
  {
    const int w = tid >> 6, l = tid & 63, l15 = l & 15, quad = l >> 4;
    const int a = w * 16 + l15;
    const float* wr = p.W_act + (size_t)a * CF + quad * 256;
    const double* hp = shd + quad * 256;
    double acc = 0.0;
    for (int kk = 0; kk < 256; kk += 4){
      acc = fma((double)wr[kk+0], hp[kk+0], acc);
      acc = fma((double)wr[kk+1], hp[kk+1], acc);
      acc = fma((double)wr[kk+2], hp[kk+2], acc);
      acc = fma((double)wr[kk+3], hp[kk+3], acc);
    }
    acc += __shfl_xor(acc, 16, 64);
    acc += __shfl_xor(acc, 32, 64);
    if (quad == 0) shd[1024 + a] = acc;
  }
  __syncthreads();
  if (tid < 64){
    double acc = shd[1024 + tid] + (double)p.b_act[tid];
    double m = acc;
    #pragma unroll
    for (int off = 32; off; off >>= 1) m = fmax(m, __shfl_xor(m, off, 64));
    unsigned long long ball = __ballot(acc == m);
    int idxv = __ffsll(ball) - 1;               // first max == np.argmax
    idxv = idxv < 0 ? 0 : (idxv > 63 ? 63 : idxv);
    double e = exp(acc - m);
    double ssum = e;
    #pragma unroll
    for (int off = 32; off; off >>= 1) ssum += __shfl_xor(ssum, off, 64);
    p.out[(size_t)b * (NSTEP * NA) + s * NA + tid] = (float)(e / ssum);
    if (tid == 0){
      p.idxb[b] = idxv;
      shd[1089] = (double)idxv;
      if (s > 0) p.out[TS_OFF + b * NSTEP + (s - 1)] = (float)shd[1088];
    }
  }
  __syncthreads();
  const float ts_val = (float)shd[1088];
  const int idxv = (int)shd[1089];
  const int c0 = tid * 4;
  const float* gb = p.gacc_t   + (size_t)b * G4;   // includes pre_t (biases folded)
  const float* eb = p.E_proj_t + (size_t)idxv * G4;
  f32x4 gi = *(const f32x4*)(gb + 0*CF + c0) + *(const f32x4*)(eb + 0*CF + c0) + ts_val * *(const f32x4*)(p.colt + 0*CF + c0);
  f32x4 gf = *(const f32x4*)(gb + 1*CF + c0) + *(const f32x4*)(eb + 1*CF + c0) + ts_val * *(const f32x4*)(p.colt + 1*CF + c0);
  f32x4 gg = *(const f32x4*)(gb + 2*CF + c0) + *(const f32x4*)(eb + 2*CF + c0) + ts_val * *(const f32x4*)(p.colt + 2*CF + c0);
  f32x4 go = *(const f32x4*)(gb + 3*CF + c0) + *(const f32x4*)(eb + 3*CF + c0) + ts_val * *(const f32x4*)(p.colt + 3*CF + c0);
  f32x4 cv = *(f32x4*)(p.c_t + (size_t)b * CF + c0);
  f32x4 cn, hn;
  #pragma unroll
  for (int jj = 0; jj < 4; ++jj){
    float cj = sigf(gf[jj]) * cv[jj] + sigf(gi[jj]) * tanhf_(gg[jj]);
    float hj = sigf(go[jj]) * tanhf_(cj);
    cn[jj] = cj; hn[jj] = hj;
  }
  *(f32x4*)(p.c_t + (size_t)b * CF + c0) = cn;
  *(f32x4*)(p.h_t + (size_t)cur * BB * CF + (size_t)b * CF + c0) = hn;
  __syncthreads();
  if (tid == 0) p.ts_accum[b] = 0.f;   // ready for next step's tshead accumulation
}

// final ts head for step 63 (h_t buffer 0) + write
__global__ void __launch_bounds__(NT) k_tsfin(P p){
  tshead_j(p, blockIdx.x, 0);
}
__global__ void __launch_bounds__(NT) k_tswrite(P p){
  p.out[TS_OFF + threadIdx.x * NSTEP + 63] = p.ts_accum[threadIdx.x] + p.b_ts2[0];
}

extern "C" void kernel_launch(void* const* d_in, const int* in_sizes, int n_in,
                              void* d_out, int out_size, void* d_ws, size_t ws_size,
                              hipStream_t stream){
  (void)in_sizes; (void)n_in; (void)out_size; (void)ws_size;
  P p;
  p.z     = (const float*)d_in[0];  p.W_z2t = (const float*)d_in[1];  p.b_z2t = (const float*)d_in[2];
  p.E     = (const float*)d_in[3];  p.Wih_a = (const float*)d_in[4];  p.Whh_a = (const float*)d_in[5];
  p.bih_a = (const float*)d_in[6];  p.bhh_a = (const float*)d_in[7];  p.Wih_t = (const float*)d_in[8];
  p.Whh_t = (const float*)d_in[9];  p.bih_t = (const float*)d_in[10]; p.bhh_t = (const float*)d_in[11];
  p.W_act = (const float*)d_in[12]; p.b_act = (const float*)d_in[13]; p.W_ts1 = (const float*)d_in[14];
  p.b_ts1 = (const float*)d_in[15]; p.W_ts2 = (const float*)d_in[16]; p.b_ts2 = (const float*)d_in[17];
  p.out = (float*)d_out;
  char* w = (char*)d_ws;
  size_t off = 0;
  auto alloc = [&](size_t bytes) -> void* { void* r = w + off; off += (bytes + 255) & ~(size_t)255; return r; };
  p.t_rec64    = (double*)alloc((size_t)BB * TD * 8);
  p.pre_a64    = (double*)alloc((size_t)BB * G4 * 8);
  p.E_proj_a64 = (double*)alloc((size_t)NA * G4 * 8);
  p.h_a64      = (double*)alloc((size_t)2 * BB * CF * 8);
  p.c_a64      = (double*)alloc((size_t)BB * CF * 8);
  p.gacc_a     = (double*)alloc((size_t)BB * G4 * 8);
  p.t_rec32    = (float*)alloc((size_t)BB * TD * 4);
  p.pre_t      = (float*)alloc((size_t)BB * G4 * 4);
  p.E_proj_t   = (float*)alloc((size_t)NA * G4 * 4);
  p.colt       = (float*)alloc((size_t)G4 * 4);
  p.h_t        = (float*)alloc((size_t)2 * BB * CF * 4);
  p.c_t        = (float*)alloc((size_t)BB * CF * 4);
  p.gacc_t     = (float*)alloc((size_t)BB * G4 * 4);
  p.ts_accum   = (float*)alloc((size_t)BB * 4);
  p.idxb       = (int*)  alloc((size_t)BB * 4);

  k_setup<<<dim3(256), dim3(NT), 0, stream>>>(p);
  k_eproj<<<dim3(528), dim3(NT), 0, stream>>>(p);
  k_pre  <<<dim3(512), dim3(NT), 0, stream>>>(p);
  for (int s = 0; s < NSTEP; ++s){
    k_stepA<<<dim3(512), dim3(NT), 0, stream>>>(p, s);
    k_stepB<<<dim3(256), dim3(NT), 0, stream>>>(p, s);
  }
  k_tsfin  <<<dim3(512), dim3(NT), 0, stream>>>(p);
  k_tswrite<<<dim3(1),   dim3(NT), 0, stream>>>(p);
}

// Round 14
// 10102.862 us; speedup vs baseline: 2.1833x; 2.1833x over previous
//
#include <hip/hip_runtime.h>
#include <stdint.h>

typedef unsigned int u32;
typedef float  f32x4 __attribute__((ext_vector_type(4)));
typedef float  f32x2 __attribute__((ext_vector_type(2)));
typedef double f64x2 __attribute__((ext_vector_type(2)));
typedef double f64x4 __attribute__((ext_vector_type(4)));

constexpr int NT  = 256;  // threads (setup/pre/stepB/tsfin)
constexpr int NTA = 128;  // threads (stepA: 2 waves per block)
constexpr int BB = 256;
constexpr int ZD = 256;
constexpr int TD = 512;
constexpr int CF = 1024;
constexpr int G4 = 4096;
constexpr int NA = 64;
constexpr int NSTEP = 64;
constexpr int TS_OFF = BB * NSTEP * NA;   // acts [256][64][64] then ts [256][64]

// k_pre LDS cores (round-3/12 proven): RSF=34 f64 rows (16B-aligned), FRS=68 f32 + XOR swizzle.
constexpr int RSF = 34;
constexpr int FRS = 68;
constexpr int SMEMB = 2 * 64 * RSF * 8;   // 34816 B

// stepA small-tile cores (16 waves/CU): a-block 32x32 via 2 waves of 16x32;
// t-block 32x32 via 128 threads of 2x4. All LDS strides even (alignment rule, round 10).
constexpr int ARS_A = 34;                  // a: f64 A rows / f32 B rows, pair-permuted
constexpr int ASZ_A = 32 * ARS_A * 8;      // 8704 B
constexpr int BSZ_A = 32 * ARS_A * 4;      // 4352 B
constexpr int TRS   = 36;                  // t: [32k][36] f32, col ^ (8*(k>>3)) swizzle
constexpr int TSZ   = 32 * TRS * 4;        // 4608 B
constexpr int SMEMA = (ASZ_A + BSZ_A) > (2 * TSZ) ? (ASZ_A + BSZ_A) : (2 * TSZ);  // 13056 B

struct P {
  const float *z, *W_z2t, *b_z2t, *E, *Wih_a, *Whh_a, *bih_a, *bhh_a,
              *Wih_t, *Whh_t, *bih_t, *bhh_t, *W_act, *b_act, *W_ts1, *b_ts1, *W_ts2, *b_ts2;
  float* out;                                               // float32 output (ref dtype)
  // f64 argmax-critical path
  double *t_rec64, *pre_a64, *E_proj_a64, *h_a64, *c_a64, *gacc_a;  // h_a64 dbuf [2][256][1024]
  // f32 ts path
  float *t_rec32, *pre_t, *E_proj_t, *colt, *h_t, *c_t, *gacc_t, *ts_accum;  // h_t dbuf [2][..]
  int* idxb;
};

__device__ __forceinline__ float sigf(float x){ return 1.f / (1.f + expf(-x)); }
__device__ __forceinline__ float tanhf_(float x){
  float ax = fabsf(x); float e = expf(-2.f * ax);
  float t = 1.f - 2.f * e / (1.f + e);
  return x < 0.f ? -t : t;
}
__device__ __forceinline__ double sigd(double x){ return 1.0 / (1.0 + exp(-x)); }

// ---------------- setup: t_rec (f64+f32), state init ----------------
__global__ void __launch_bounds__(NT) k_setup(P p){
  __shared__ double sz[ZD];
  const int bid = blockIdx.x, tid = threadIdx.x;
  for (int i = tid; i < ZD; i += NT) sz[i] = (double)p.z[bid * ZD + i];
  __syncthreads();
  for (int k = tid; k < TD; k += NT){
    const float* wr = p.W_z2t + (size_t)k * ZD;
    double a = 0.0;
    for (int j = 0; j < ZD; ++j) a = fma((double)wr[j], sz[j], a);
    a += (double)p.b_z2t[k];
    double t = a > 0.0 ? a : 0.0;
    p.t_rec64[(size_t)bid * TD + k] = t;
    p.t_rec32[(size_t)bid * TD + k] = (float)t;
  }
  for (int i = tid; i < CF; i += NT){
    p.c_a64[(size_t)bid * CF + i] = 0.0;
    p.h_a64[(size_t)bid * CF + i] = 0.0;  // buffer 0
    p.c_t[(size_t)bid * CF + i] = 0.f;
    p.h_t[(size_t)bid * CF + i] = 0.f;    // buffer 0
  }
  if (tid == 0){ p.idxb[bid] = NA - 1; p.ts_accum[bid] = 0.f; }
}

// ---------------- E_proj tables + colt. grid 528 ----------------
__global__ void __launch_bounds__(NT) k_eproj(P p){
  __shared__ double sz[ZD];
  const int bid = blockIdx.x, tid = threadIdx.x;
  if (bid < 256){            // E_proj_a64: row bid>>2, col chunk bid&3 (1024 cols)
    const int erow = bid >> 2, cchunk = bid & 3;
    for (int i = tid; i < ZD; i += NT) sz[i] = (double)p.E[erow * ZD + i];
    __syncthreads();
    for (int ci = 0; ci < 4; ++ci){
      const int c = cchunk * 1024 + ci * 256 + tid;
      const float* wr = p.Wih_a + (size_t)c * 768 + 512;
      double a = 0.0;
      for (int j = 0; j < 256; ++j) a = fma((double)wr[j], sz[j], a);
      p.E_proj_a64[(size_t)erow * G4 + c] = a;
    }
  } else if (bid < 512){     // E_proj_t (f32)
    const int erow = (bid - 256) >> 2, cchunk = (bid - 256) & 3;
    for (int i = tid; i < ZD; i += NT) sz[i] = (double)p.E[erow * ZD + i];
    __syncthreads();
    for (int ci = 0; ci < 4; ++ci){
      const int c = cchunk * 1024 + ci * 256 + tid;
      const float* wr = p.Wih_t + (size_t)c * 769 + 512;
      float a = 0.f;
      for (int j = 0; j < 256; ++j) a = fmaf(wr[j], (float)sz[j], a);
      p.E_proj_t[(size_t)erow * G4 + c] = a;
    }
  } else {                   // colt
    const int c = (bid - 512) * 256 + tid;
    p.colt[c] = p.Wih_t[(size_t)c * 769 + 768];
  }
}

// ---------------- k_pre f64 MFMA core (LDS, 256 thr, round-3 proven; odd ldb ok) ----------------
template <bool A64, bool OUT64>
__device__ void mgemm64s(char* smem, const void* __restrict__ Av, int lda,
                         const float* __restrict__ B, int ldb,
                         int rowb, int colb, int K,
                         const float* __restrict__ bih, const float* __restrict__ bhh,
                         void* __restrict__ outv){
  double* As = (double*)smem;
  double* Bs = As + 64 * RSF;
  const int tid = threadIdx.x;
  const int lane = tid & 63;
  const int wm = (tid >> 7) & 1, wn = (tid >> 6) & 1;
  const int m = lane & 15, q = lane >> 4;
  const int tr = tid >> 2, tkq = tid & 3;
  const double* A64p = (const double*)Av;
  const float*  A32p = (const float*)Av;

  double av[8], bv[8];
  auto loadchunk = [&](int kb){
    if (A64){
      const double* ap = A64p + (size_t)(rowb + tr) * lda + kb + tkq * 8;
      #pragma unroll
      for (int j = 0; j < 8; ++j) av[j] = ap[j];
    } else {
      const float* ap = A32p + (size_t)(rowb + tr) * lda + kb + tkq * 8;
      #pragma unroll
      for (int j = 0; j < 8; ++j) av[j] = (double)ap[j];
    }
    const float* bp = B + (size_t)(colb + tr) * ldb + kb + tkq * 8;
    #pragma unroll
    for (int j = 0; j < 8; ++j) bv[j] = (double)bp[j];
  };
  f64x4 acc[2][2];
  #pragma unroll
  for (int g = 0; g < 2; ++g)
    #pragma unroll
    for (int h = 0; h < 2; ++h) acc[g][h] = f64x4{0.0,0.0,0.0,0.0};

  loadchunk(0);
  for (int kb = 0; kb < K; kb += 32){
    __syncthreads();
    {
      double* arow = As + tr * RSF + tkq * 8;
      double* brow = Bs + tr * RSF + tkq * 8;
      #pragma unroll
      for (int j = 0; j < 4; ++j){
        *(f64x2*)(arow + j * 2) = f64x2{av[j], av[j + 4]};
        *(f64x2*)(brow + j * 2) = f64x2{bv[j], bv[j + 4]};
      }
    }
    __syncthreads();
    if (kb + 32 < K) loadchunk(kb + 32);
    #pragma unroll
    for (int sp = 0; sp < 4; ++sp){
      const f64x2 a0 = *(const f64x2*)(As + (wm * 32 +  0 + m) * RSF + sp * 8 + q * 2);
      const f64x2 a1 = *(const f64x2*)(As + (wm * 32 + 16 + m) * RSF + sp * 8 + q * 2);
      const f64x2 b0 = *(const f64x2*)(Bs + (wn * 32 +  0 + m) * RSF + sp * 8 + q * 2);
      const f64x2 b1 = *(const f64x2*)(Bs + (wn * 32 + 16 + m) * RSF + sp * 8 + q * 2);
      acc[0][0] = __builtin_amdgcn_mfma_f64_16x16x4f64(a0[0], b0[0], acc[0][0], 0, 0, 0);
      acc[0][1] = __builtin_amdgcn_mfma_f64_16x16x4f64(a0[0], b1[0], acc[0][1], 0, 0, 0);
      acc[1][0] = __builtin_amdgcn_mfma_f64_16x16x4f64(a1[0], b0[0], acc[1][0], 0, 0, 0);
      acc[1][1] = __builtin_amdgcn_mfma_f64_16x16x4f64(a1[0], b1[0], acc[1][1], 0, 0, 0);
      acc[0][0] = __builtin_amdgcn_mfma_f64_16x16x4f64(a0[1], b0[1], acc[0][0], 0, 0, 0);
      acc[0][1] = __builtin_amdgcn_mfma_f64_16x16x4f64(a0[1], b1[1], acc[0][1], 0, 0, 0);
      acc[1][0] = __builtin_amdgcn_mfma_f64_16x16x4f64(a1[1], b0[1], acc[1][0], 0, 0, 0);
      acc[1][1] = __builtin_amdgcn_mfma_f64_16x16x4f64(a1[1], b1[1], acc[1][1], 0, 0, 0);
    }
  }
  #pragma unroll
  for (int g = 0; g < 2; ++g){
    const int rb = rowb + wm * 32 + g * 16 + q;
    #pragma unroll
    for (int h = 0; h < 2; ++h){
      const int cc = colb + wn * 32 + h * 16 + m;
      const double bb = (double)bih[cc] + (double)bhh[cc];
      #pragma unroll
      for (int v = 0; v < 4; ++v){
        if (OUT64) ((double*)outv)[(size_t)(rb + 4 * v) * G4 + cc] = acc[g][h][v] + bb;
        else       ((float*) outv)[(size_t)(rb + 4 * v) * G4 + cc] = (float)(acc[g][h][v] + bb);
      }
    }
  }
}

// ---------------- k_pre f32 core (LDS + XOR swizzle, 256 thr, round-12 proven) ----------------
__device__ void dgemm32s(char* smem, const float* __restrict__ A, int lda,
                         const float* __restrict__ B, int ldb,
                         int rowb, int colb, int K,
                         const float* __restrict__ bih, const float* __restrict__ bhh,
                         float* __restrict__ outp){
  float* As = (float*)smem;                       // [64][FRS]
  float* Bs = (float*)(smem + 64 * FRS * 4);      // [64][FRS]
  const int tid = threadIdx.x;
  const int tx = tid & 15, ty = tid >> 4;
  const int r_ = tid >> 2, kq = tid & 3;
  const int wsw = r_ ^ (kq * 8);
  float acc[4][4];
  #pragma unroll
  for (int i = 0; i < 4; ++i)
    #pragma unroll
    for (int j = 0; j < 4; ++j) acc[i][j] = 0.f;

  float pa[16], pb[16];
  auto ldA = [&](int kb){
    const float* ap = A + (size_t)(rowb + r_) * lda + kb + kq * 16;
    #pragma unroll
    for (int j = 0; j < 16; ++j) pa[j] = ap[j];
  };
  auto ldB = [&](int kb){
    const float* bp = B + (size_t)(colb + r_) * ldb + kb + kq * 16;
    #pragma unroll
    for (int j = 0; j < 16; ++j) pb[j] = bp[j];
  };
  ldA(0); ldB(0);
  for (int kb = 0; kb < K; kb += 64){
    __syncthreads();
    #pragma unroll
    for (int j = 0; j < 16; ++j){
      As[(kq * 16 + j) * FRS + wsw] = pa[j];
      Bs[(kq * 16 + j) * FRS + wsw] = pb[j];
    }
    __syncthreads();
    if (kb + 64 < K){ ldA(kb + 64); ldB(kb + 64); }
    #pragma unroll 4
    for (int k = 0; k < 64; ++k){
      const int sw = (k >> 4) * 8;
      f32x4 a4 = *(const f32x4*)(As + k * FRS + ((4 * ty) ^ sw));
      f32x4 b4 = *(const f32x4*)(Bs + k * FRS + ((4 * tx) ^ sw));
      acc[0][0] = fmaf(a4[0], b4[0], acc[0][0]); acc[0][1] = fmaf(a4[0], b4[1], acc[0][1]);
      acc[0][2] = fmaf(a4[0], b4[2], acc[0][2]); acc[0][3] = fmaf(a4[0], b4[3], acc[0][3]);
      acc[1][0] = fmaf(a4[1], b4[0], acc[1][0]); acc[1][1] = fmaf(a4[1], b4[1], acc[1][1]);
      acc[1][2] = fmaf(a4[1], b4[2], acc[1][2]); acc[1][3] = fmaf(a4[1], b4[3], acc[1][3]);
      acc[2][0] = fmaf(a4[2], b4[0], acc[2][0]); acc[2][1] = fmaf(a4[2], b4[1], acc[2][1]);
      acc[2][2] = fmaf(a4[2], b4[2], acc[2][2]); acc[2][3] = fmaf(a4[2], b4[3], acc[2][3]);
      acc[3][0] = fmaf(a4[3], b4[0], acc[3][0]); acc[3][1] = fmaf(a4[3], b4[1], acc[3][1]);
      acc[3][2] = fmaf(a4[3], b4[2], acc[3][2]); acc[3][3] = fmaf(a4[3], b4[3], acc[3][3]);
    }
  }
  const int c0 = colb + 4 * tx;
  float bb0 = bih[c0+0] + bhh[c0+0], bb1 = bih[c0+1] + bhh[c0+1];
  float bb2 = bih[c0+2] + bhh[c0+2], bb3 = bih[c0+3] + bhh[c0+3];
  #pragma unroll
  for (int i = 0; i < 4; ++i){
    float* o = outp + (size_t)(rowb + 4 * ty + i) * G4 + c0;
    o[0] = acc[i][0] + bb0; o[1] = acc[i][1] + bb1;
    o[2] = acc[i][2] + bb2; o[3] = acc[i][3] + bb3;
  }
}

// ---------------- stepA a-core: 32x32 tile, 2 waves of 16x32 (128 thr) ----------------
// Same schedule / pair-permutation / H2 epilogue as proven core; B staged f32 (exact).
__device__ void mgemm64w(char* smem, const double* __restrict__ A, int lda,
                         const float* __restrict__ B, int ldb,
                         int rowb, int colb, int K,
                         const double* __restrict__ addin, double* __restrict__ outp){
  double* As = (double*)smem;                 // [32][34] f64, pair-permuted
  float*  Bs = (float*)(smem + ASZ_A);        // [32][34] f32, pair-permuted
  const int tid = threadIdx.x, lane = tid & 63;
  const int w = tid >> 6;                     // wave -> rows 16w..16w+15
  const int m = lane & 15, q = lane >> 4;
  const int tr = tid >> 2, tkq = tid & 3;     // staging: row/col 0..31, k-octet
  double av[8]; float bv[8];
  auto loadchunk = [&](int kb){
    const double* ap = A + (size_t)(rowb + tr) * lda + kb + tkq * 8;
    #pragma unroll
    for (int j = 0; j < 8; ++j) av[j] = ap[j];
    const float* bp = B + (size_t)(colb + tr) * ldb + kb + tkq * 8;
    #pragma unroll
    for (int j = 0; j < 8; ++j) bv[j] = bp[j];
  };
  f64x4 acc0{0,0,0,0}, acc1{0,0,0,0};
  loadchunk(0);
  for (int kb = 0; kb < K; kb += 32){
    __syncthreads();
    {
      double* arow = As + tr * ARS_A + tkq * 8;
      float*  brow = Bs + tr * ARS_A + tkq * 8;
      #pragma unroll
      for (int j = 0; j < 4; ++j){            // pair (k, k+4) -> adjacent slots
        *(f64x2*)(arow + j * 2) = f64x2{av[j], av[j + 4]};
        *(f32x2*)(brow + j * 2) = f32x2{bv[j], bv[j + 4]};
      }
    }
    __syncthreads();
    if (kb + 32 < K) loadchunk(kb + 32);
    #pragma unroll
    for (int sp = 0; sp < 4; ++sp){
      const f64x2 a0  = *(const f64x2*)(As + (16 * w + m) * ARS_A + sp * 8 + q * 2);
      const f32x2 b0f = *(const f32x2*)(Bs + ( 0 + m) * ARS_A + sp * 8 + q * 2);
      const f32x2 b1f = *(const f32x2*)(Bs + (16 + m) * ARS_A + sp * 8 + q * 2);
      acc0 = __builtin_amdgcn_mfma_f64_16x16x4f64(a0[0], (double)b0f[0], acc0, 0, 0, 0);
      acc1 = __builtin_amdgcn_mfma_f64_16x16x4f64(a0[0], (double)b1f[0], acc1, 0, 0, 0);
      acc0 = __builtin_amdgcn_mfma_f64_16x16x4f64(a0[1], (double)b0f[1], acc0, 0, 0, 0);
      acc1 = __builtin_amdgcn_mfma_f64_16x16x4f64(a0[1], (double)b1f[1], acc1, 0, 0, 0);
    }
  }
  // H2 epilogue: reg v -> row base + q + 4v, col base + m
  const int rb = rowb + 16 * w + q;
  #pragma unroll
  for (int h = 0; h < 2; ++h){
    const f64x4 a = h ? acc1 : acc0;
    const int cc = colb + h * 16 + m;
    #pragma unroll
    for (int v = 0; v < 4; ++v){
      const size_t o = (size_t)(rb + 4 * v) * G4 + cc;
      outp[o] = a[v] + addin[o];
    }
  }
}

// ---------------- stepA t-core: 32x32 tile, 128 thr of 2x4, BK=32, swizzled LDS ----------------
__device__ void dgemm32w(char* smem, const float* __restrict__ A, int lda,
                         const float* __restrict__ B, int ldb,
                         int rowb, int colb, int K,
                         const float* __restrict__ addin, float* __restrict__ outp){
  float* As = (float*)smem;                   // [32k][36]: A rows 0..31
  float* Bs = (float*)(smem + TSZ);           // [32k][36]: B cols 0..31
  const int tid = threadIdx.x;
  const int tx = tid & 7, ty = tid >> 3;      // cols 4tx..+3, rows 2ty..2ty+1
  const int r_ = tid >> 2, kq = tid & 3;      // staging: row/col 0..31, 8 k each
  const int wsw = r_ ^ (kq * 8);
  float acc[2][4];
  #pragma unroll
  for (int i = 0; i < 2; ++i)
    #pragma unroll
    for (int j = 0; j < 4; ++j) acc[i][j] = 0.f;
  float pa[8], pb[8];
  auto ldAB = [&](int kb){
    const float* ap = A + (size_t)(rowb + r_) * lda + kb + kq * 8;
    #pragma unroll
    for (int j = 0; j < 8; ++j) pa[j] = ap[j];
    const float* bp = B + (size_t)(colb + r_) * ldb + kb + kq * 8;
    #pragma unroll
    for (int j = 0; j < 8; ++j) pb[j] = bp[j];
  };
  ldAB(0);
  for (int kb = 0; kb < K; kb += 32){
    __syncthreads();
    #pragma unroll
    for (int j = 0; j < 8; ++j){
      As[(kq * 8 + j) * TRS + wsw] = pa[j];
      Bs[(kq * 8 + j) * TRS + wsw] = pb[j];
    }
    __syncthreads();
    if (kb + 32 < K) ldAB(kb + 32);
    #pragma unroll 4
    for (int k = 0; k < 32; ++k){
      const int sw = (k >> 3) * 8;
      f32x2 a2 = *(const f32x2*)(As + k * TRS + ((2 * ty) ^ sw));
      f32x4 b4 = *(const f32x4*)(Bs + k * TRS + ((4 * tx) ^ sw));
      acc[0][0] = fmaf(a2[0], b4[0], acc[0][0]); acc[0][1] = fmaf(a2[0], b4[1], acc[0][1]);
      acc[0][2] = fmaf(a2[0], b4[2], acc[0][2]); acc[0][3] = fmaf(a2[0], b4[3], acc[0][3]);
      acc[1][0] = fmaf(a2[1], b4[0], acc[1][0]); acc[1][1] = fmaf(a2[1], b4[1], acc[1][1]);
      acc[1][2] = fmaf(a2[1], b4[2], acc[1][2]); acc[1][3] = fmaf(a2[1], b4[3], acc[1][3]);
    }
  }
  const int c0 = colb + 4 * tx;
  #pragma unroll
  for (int i = 0; i < 2; ++i){
    const size_t base = (size_t)(rowb + 2 * ty + i) * G4 + c0;
    const float* ai = addin + base;
    float* o = outp + base;
    o[0] = acc[i][0] + ai[0]; o[1] = acc[i][1] + ai[1];
    o[2] = acc[i][2] + ai[2]; o[3] = acc[i][3] + ai[3];
  }
}

// ---------------- ts head (256 thr, k_tsfin): 512 jobs of 8 j-rows ----------------
__device__ void tshead_j(const P& p, int bid, int hbuf){
  const int tid = threadIdx.x;
  const int tm = bid >> 6, tjq = bid & 63;
  const int rowb = tm * 32;
  const int rt = tid >> 3, j8 = tid & 7;
  const int j = tjq * 8 + j8;
  const float* __restrict__ hr = p.h_t + (size_t)hbuf * BB * CF + (size_t)(rowb + rt) * CF;
  const float* __restrict__ wr = p.W_ts1 + (size_t)j * CF;
  float a0=0,a1=0,a2=0,a3=0;
  for (int k = 0; k < CF; k += 16){
    f32x4 h0 = *(const f32x4*)(hr + k),     h1 = *(const f32x4*)(hr + k + 4);
    f32x4 h2 = *(const f32x4*)(hr + k + 8), h3 = *(const f32x4*)(hr + k + 12);
    f32x4 w0 = *(const f32x4*)(wr + k),     w1 = *(const f32x4*)(wr + k + 4);
    f32x4 w2 = *(const f32x4*)(wr + k + 8), w3 = *(const f32x4*)(wr + k + 12);
    a0 = fmaf(h0[0],w0[0], fmaf(h0[1],w0[1], fmaf(h0[2],w0[2], fmaf(h0[3],w0[3], a0))));
    a1 = fmaf(h1[0],w1[0], fmaf(h1[1],w1[1], fmaf(h1[2],w1[2], fmaf(h1[3],w1[3], a1))));
    a2 = fmaf(h2[0],w2[0], fmaf(h2[1],w2[1], fmaf(h2[2],w2[2], fmaf(h2[3],w2[3], a2))));
    a3 = fmaf(h3[0],w3[0], fmaf(h3[1],w3[1], fmaf(h3[2],w3[2], fmaf(h3[3],w3[3], a3))));
  }
  float v = ((a0 + a1) + (a2 + a3)) + p.b_ts1[j];
  v = (v > 0.f ? v : 0.f) * p.W_ts2[j];
  v += __shfl_xor(v, 1, 64);
  v += __shfl_xor(v, 2, 64);
  v += __shfl_xor(v, 4, 64);
  if (j8 == 0) atomicAdd(p.ts_accum + rowb + rt, v);
}

// ---------------- ts head (128 thr, stepA): 1024 jobs of 4 j-rows ----------------
__device__ void tshead_j128(const P& p, int bid, int hbuf){
  const int tid = threadIdx.x;
  const int tm = bid >> 7, tjq = bid & 127;   // tm 0..7, tjq 0..127
  const int rowb = tm * 32;
  const int rt = tid >> 2, j4 = tid & 3;      // rt 0..31
  const int j = tjq * 4 + j4;                 // 0..511
  const float* __restrict__ hr = p.h_t + (size_t)hbuf * BB * CF + (size_t)(rowb + rt) * CF;
  const float* __restrict__ wr = p.W_ts1 + (size_t)j * CF;
  float a0=0,a1=0,a2=0,a3=0;
  for (int k = 0; k < CF; k += 16){
    f32x4 h0 = *(const f32x4*)(hr + k),     h1 = *(const f32x4*)(hr + k + 4);
    f32x4 h2 = *(const f32x4*)(hr + k + 8), h3 = *(const f32x4*)(hr + k + 12);
    f32x4 w0 = *(const f32x4*)(wr + k),     w1 = *(const f32x4*)(wr + k + 4);
    f32x4 w2 = *(const f32x4*)(wr + k + 8), w3 = *(const f32x4*)(wr + k + 12);
    a0 = fmaf(h0[0],w0[0], fmaf(h0[1],w0[1], fmaf(h0[2],w0[2], fmaf(h0[3],w0[3], a0))));
    a1 = fmaf(h1[0],w1[0], fmaf(h1[1],w1[1], fmaf(h1[2],w1[2], fmaf(h1[3],w1[3], a1))));
    a2 = fmaf(h2[0],w2[0], fmaf(h2[1],w2[1], fmaf(h2[2],w2[2], fmaf(h2[3],w2[3], a2))));
    a3 = fmaf(h3[0],w3[0], fmaf(h3[1],w3[1], fmaf(h3[2],w3[2], fmaf(h3[3],w3[3], a3))));
  }
  float v = ((a0 + a1) + (a2 + a3)) + p.b_ts1[j];
  v = (v > 0.f ? v : 0.f) * p.W_ts2[j];
  v += __shfl_xor(v, 1, 64);
  v += __shfl_xor(v, 2, 64);
  if (j4 == 0) atomicAdd(p.ts_accum + rowb + rt, v);
}

// ---------------- pre kernel (256 thr, LDS cores). grid 512 ----------------
__global__ void __launch_bounds__(NT) k_pre(P p){
  __shared__ __align__(16) char smem[SMEMB];
  const int bid = blockIdx.x;
  const int hsel = bid >> 8, sub = bid & 255;
  const int rowb = (sub >> 6) * 64, colb = (sub & 63) * 64;
  if (hsel == 0)
    mgemm64s<true, true>(smem, p.t_rec64, TD, p.Wih_a, 768, rowb, colb, TD,
                         p.bih_a, p.bhh_a, p.pre_a64);
  else
    dgemm32s(smem, p.t_rec32, TD, p.Wih_t, 769, rowb, colb, TD,
             p.bih_t, p.bhh_t, p.pre_t);
}

// ---------------- step A: ts head + recurrent GEMMs, small tiles. grid 2048 x 128 ----------------
// bid 0..1023 = a-tiles (32x32, MFMA), 1024..2047 = t-tiles (32x32, VALU).
// colb fast -> XCD-stable B-panel partitioning. tshead rides on the a-blocks.
__global__ void __launch_bounds__(NTA) k_stepA(P p, int s){
  __shared__ __align__(16) char smem[SMEMA];
  const int bid = blockIdx.x;
  if (s > 0 && bid < 1024) tshead_j128(p, bid, s & 1);  // ts head for step s-1
  const int hsel = bid >> 10, sub = bid & 1023;
  const int rowb = (sub >> 7) * 32, colb = (sub & 127) * 32;
  const int rd = s & 1;
  if (hsel == 0)
    mgemm64w(smem, p.h_a64 + (size_t)rd * BB * CF, CF, p.Whh_a, CF,
             rowb, colb, CF, p.pre_a64, p.gacc_a);
  else
    dgemm32w(smem, p.h_t + (size_t)rd * BB * CF, CF, p.Whh_t, CF,
             rowb, colb, CF, p.pre_t, p.gacc_t);
}

// ---------------- step B: LSTM-a pointwise (f64) + logits/argmax/softmax (f64) + LSTM-t (f32) ----------------
__global__ void __launch_bounds__(NT) k_stepB(P p, int s){
  __shared__ double shd[1092];
  const int b = blockIdx.x, tid = threadIdx.x;
  const int cur = (s + 1) & 1;   // h_a/h_t write buffer
  int idxp = p.idxb[b];
  idxp = idxp < 0 ? 0 : (idxp > 63 ? 63 : idxp);
  {
    const double* ga = p.gacc_a + (size_t)b * G4;       // includes pre_a (biases folded)
    const double* ea = p.E_proj_a64 + (size_t)idxp * G4;
    const int c0 = tid * 4;
    #pragma unroll
    for (int jj = 0; jj < 4; ++jj){
      const int c = c0 + jj;
      double gi = ga[0*CF + c] + ea[0*CF + c];
      double gf = ga[1*CF + c] + ea[1*CF + c];
      double gg = ga[2*CF + c] + ea[2*CF + c];
      double go = ga[3*CF + c] + ea[3*CF + c];
      double cv = p.c_a64[(size_t)b * CF + c];
      double cn = sigd(gf) * cv + sigd(gi) * tanh(gg);
      double hn = sigd(go) * tanh(cn);
      p.c_a64[(size_t)b * CF + c] = cn;
      p.h_a64[(size_t)cur * BB * CF + (size_t)b * CF + c] = hn;
      shd[c] = hn;
    }
  }
  if (tid == 0) shd[1088] = (s == 0) ? 0.0 : ((double)p.ts_accum[b] + (double)p.b_ts2[0]);
  __syncthreads();
  {
    const int w = tid >> 6, l = tid & 63, l15 = l & 15, quad = l >> 4;
    const int a = w * 16 + l15;
    const float* wr = p.W_act + (size_t)a * CF + quad * 256;
    const double* hp = shd + quad * 256;
    double acc = 0.0;
    for (int kk = 0; kk < 256; kk += 4){
      acc = fma((double)wr[kk+0], hp[kk+0], acc);
      acc = fma((double)wr[kk+1], hp[kk+1], acc);
      acc = fma((double)wr[kk+2], hp[kk+2], acc);
      acc = fma((double)wr[kk+3], hp[kk+3], acc);
    }
    acc += __shfl_xor(acc, 16, 64);
    acc += __shfl_xor(acc, 32, 64);
    if (quad == 0) shd[1024 + a] = acc;
  }
  __syncthreads();
  if (tid < 64){
    double acc = shd[1024 + tid] + (double)p.b_act[tid];
    double m = acc;
    #pragma unroll
    for (int off = 32; off; off >>= 1) m = fmax(m, __shfl_xor(m, off, 64));
    unsigned long long ball = __ballot(acc == m);
    int idxv = __ffsll(ball) - 1;               // first max == np.argmax
    idxv = idxv < 0 ? 0 : (idxv > 63 ? 63 : idxv);
    double e = exp(acc - m);
    double ssum = e;
    #pragma unroll
    for (int off = 32; off; off >>= 1) ssum += __shfl_xor(ssum, off, 64);
    p.out[(size_t)b * (NSTEP * NA) + s * NA + tid] = (float)(e / ssum);
    if (tid == 0){
      p.idxb[b] = idxv;
      shd[1089] = (double)idxv;
      if (s > 0) p.out[TS_OFF + b * NSTEP + (s - 1)] = (float)shd[1088];
    }
  }
  __syncthreads();
  const float ts_val = (float)shd[1088];
  const int idxv = (int)shd[1089];
  const int c0 = tid * 4;
  const float* gb = p.gacc_t   + (size_t)b * G4;   // includes pre_t (biases folded)
  const float* eb = p.E_proj_t + (size_t)idxv * G4;
  f32x4 gi = *(const f32x4*)(gb + 0*CF + c0) + *(const f32x4*)(eb + 0*CF + c0) + ts_val * *(const f32x4*)(p.colt + 0*CF + c0);
  f32x4 gf = *(const f32x4*)(gb + 1*CF + c0) + *(const f32x4*)(eb + 1*CF + c0) + ts_val * *(const f32x4*)(p.colt + 1*CF + c0);
  f32x4 gg = *(const f32x4*)(gb + 2*CF + c0) + *(const f32x4*)(eb + 2*CF + c0) + ts_val * *(const f32x4*)(p.colt + 2*CF + c0);
  f32x4 go = *(const f32x4*)(gb + 3*CF + c0) + *(const f32x4*)(eb + 3*CF + c0) + ts_val * *(const f32x4*)(p.colt + 3*CF + c0);
  f32x4 cv = *(f32x4*)(p.c_t + (size_t)b * CF + c0);
  f32x4 cn, hn;
  #pragma unroll
  for (int jj = 0; jj < 4; ++jj){
    float cj = sigf(gf[jj]) * cv[jj] + sigf(gi[jj]) * tanhf_(gg[jj]);
    float hj = sigf(go[jj]) * tanhf_(cj);
    cn[jj] = cj; hn[jj] = hj;
  }
  *(f32x4*)(p.c_t + (size_t)b * CF + c0) = cn;
  *(f32x4*)(p.h_t + (size_t)cur * BB * CF + (size_t)b * CF + c0) = hn;
  __syncthreads();
  if (tid == 0) p.ts_accum[b] = 0.f;   // ready for next step's tshead accumulation
}

// final ts head for step 63 (h_t buffer 0) + write
__global__ void __launch_bounds__(NT) k_tsfin(P p){
  tshead_j(p, blockIdx.x, 0);
}
__global__ void __launch_bounds__(NT) k_tswrite(P p){
  p.out[TS_OFF + threadIdx.x * NSTEP + 63] = p.ts_accum[threadIdx.x] + p.b_ts2[0];
}

extern "C" void kernel_launch(void* const* d_in, const int* in_sizes, int n_in,
                              void* d_out, int out_size, void* d_ws, size_t ws_size,
                              hipStream_t stream){
  (void)in_sizes; (void)n_in; (void)out_size; (void)ws_size;
  P p;
  p.z     = (const float*)d_in[0];  p.W_z2t = (const float*)d_in[1];  p.b_z2t = (const float*)d_in[2];
  p.E     = (const float*)d_in[3];  p.Wih_a = (const float*)d_in[4];  p.Whh_a = (const float*)d_in[5];
  p.bih_a = (const float*)d_in[6];  p.bhh_a = (const float*)d_in[7];  p.Wih_t = (const float*)d_in[8];
  p.Whh_t = (const float*)d_in[9];  p.bih_t = (const float*)d_in[10]; p.bhh_t = (const float*)d_in[11];
  p.W_act = (const float*)d_in[12]; p.b_act = (const float*)d_in[13]; p.W_ts1 = (const float*)d_in[14];
  p.b_ts1 = (const float*)d_in[15]; p.W_ts2 = (const float*)d_in[16]; p.b_ts2 = (const float*)d_in[17];
  p.out = (float*)d_out;
  char* w = (char*)d_ws;
  size_t off = 0;
  auto alloc = [&](size_t bytes) -> void* { void* r = w + off; off += (bytes + 255) & ~(size_t)255; return r; };
  p.t_rec64    = (double*)alloc((size_t)BB * TD * 8);
  p.pre_a64    = (double*)alloc((size_t)BB * G4 * 8);
  p.E_proj_a64 = (double*)alloc((size_t)NA * G4 * 8);
  p.h_a64      = (double*)alloc((size_t)2 * BB * CF * 8);
  p.c_a64      = (double*)alloc((size_t)BB * CF * 8);
  p.gacc_a     = (double*)alloc((size_t)BB * G4 * 8);
  p.t_rec32    = (float*)alloc((size_t)BB * TD * 4);
  p.pre_t      = (float*)alloc((size_t)BB * G4 * 4);
  p.E_proj_t   = (float*)alloc((size_t)NA * G4 * 4);
  p.colt       = (float*)alloc((size_t)G4 * 4);
  p.h_t        = (float*)alloc((size_t)2 * BB * CF * 4);
  p.c_t        = (float*)alloc((size_t)BB * CF * 4);
  p.gacc_t     = (float*)alloc((size_t)BB * G4 * 4);
  p.ts_accum   = (float*)alloc((size_t)BB * 4);
  p.idxb       = (int*)  alloc((size_t)BB * 4);

  k_setup<<<dim3(256), dim3(NT), 0, stream>>>(p);
  k_eproj<<<dim3(528), dim3(NT), 0, stream>>>(p);
  k_pre  <<<dim3(512), dim3(NT), 0, stream>>>(p);
  for (int s = 0; s < NSTEP; ++s){
    k_stepA<<<dim3(2048), dim3(NTA), 0, stream>>>(p, s);
    k_stepB<<<dim3(256),  dim3(NT),  0, stream>>>(p, s);
  }
  k_tsfin  <<<dim3(512), dim3(NT), 0, stream>>>(p);
  k_tswrite<<<dim3(1),   dim3(NT), 0, stream>>>(p);
}